// Round 1
// baseline (6055.722 us; speedup 1.0000x reference)
//
#include <hip/hip_runtime.h>
#include <math.h>

#define T_STEPS 64
#define BB 64
#define LL 2048
#define EE 128
#define HH 256
#define NCHUNK 16
#define LCHUNK (LL / NCHUNK) /* 128 */

__device__ __forceinline__ float fexp(float x) {
    // e^x = 2^(x*log2e); exp2(-inf)=0 as needed for online-softmax init
    return __builtin_amdgcn_exp2f(x * 1.44269504088896340736f);
}
__device__ __forceinline__ float fsig(float x) {
    return __builtin_amdgcn_rcpf(1.f + __builtin_amdgcn_exp2f(-1.44269504088896340736f * x));
}
__device__ __forceinline__ float ftanh(float x) {
    float xc = fminf(fmaxf(x, -20.f), 20.f);
    float p = __builtin_amdgcn_exp2f(2.885390081777926814f * xc); // e^{2x}
    return (p - 1.f) * __builtin_amdgcn_rcpf(p + 1.f);
}

// ---------------------------------------------------------------------------
// Attention main pass: one wave per (b,l) row, enc row kept in registers.
// Computes e_bl (stored) and online-softmax partial (m, s, ctx) per block.
// Grid: NCHUNK*BB blocks (chunk = bid>>6, b = bid&63), 256 threads (4 waves).
// ---------------------------------------------------------------------------
__global__ __launch_bounds__(256) void attn_kernel(
    const float* __restrict__ enc,   // (B,L,H)
    const float* __restrict__ mask,  // (B,L)
    const float* __restrict__ covp,  // (B,L) current coverage
    const float* __restrict__ df,    // (B,H) dec_feat
    const float* __restrict__ v,     // (H)
    const float* __restrict__ wc,    // (H)
    float* __restrict__ e_ws,        // (B,L)
    float* __restrict__ mp,          // (NCHUNK*B)
    float* __restrict__ sp,          // (NCHUNK*B)
    float* __restrict__ ctxp)        // (NCHUNK*B*H)
{
    const int g = blockIdx.x;
    const int b = g & (BB - 1);
    const int chunk = g >> 6;
    const int tid = threadIdx.x;
    const int wave = tid >> 6;
    const int lane = tid & 63;
    const int l0 = chunk * LCHUNK + wave * (LCHUNK / 4);

    const float4 df4 = *(const float4*)(df + b * HH + lane * 4);
    const float4 v4  = *(const float4*)(v + lane * 4);
    const float4 wc4 = *(const float4*)(wc + lane * 4);

    float m = -INFINITY, s = 0.f;
    float4 cacc = make_float4(0.f, 0.f, 0.f, 0.f);

    const float4* encp = (const float4*)enc + (size_t)(b * LL + l0) * (HH / 4) + lane;

    for (int i = 0; i < LCHUNK / 4; ++i) {
        const int l = l0 + i;
        const float4 ev = encp[i * (HH / 4)];
        const float cv = covp[b * LL + l];
        const float msk = mask[b * LL + l];

        float t0 = ftanh(ev.x + df4.x + cv * wc4.x);
        float t1 = ftanh(ev.y + df4.y + cv * wc4.y);
        float t2 = ftanh(ev.z + df4.z + cv * wc4.z);
        float t3 = ftanh(ev.w + df4.w + cv * wc4.w);
        float p = v4.x * t0 + v4.y * t1 + v4.z * t2 + v4.w * t3;
        #pragma unroll
        for (int off = 32; off; off >>= 1) p += __shfl_xor(p, off);
        if (lane == 0) e_ws[b * LL + l] = p;

        // branchless online-softmax update (wave-uniform p)
        const float mn = fmaxf(m, p);
        const float sc = fexp(m - mn);        // 0 on first iter (m=-inf)
        const float w  = fexp(p - mn) * msk;
        s = s * sc + w;
        cacc.x = cacc.x * sc + w * ev.x;
        cacc.y = cacc.y * sc + w * ev.y;
        cacc.z = cacc.z * sc + w * ev.z;
        cacc.w = cacc.w * sc + w * ev.w;
        m = mn;
    }

    // block-level combine of the 4 wave partials
    __shared__ float lm[4], ls[4];
    __shared__ float lctx[4][HH];
    lctx[wave][lane * 4 + 0] = cacc.x;
    lctx[wave][lane * 4 + 1] = cacc.y;
    lctx[wave][lane * 4 + 2] = cacc.z;
    lctx[wave][lane * 4 + 3] = cacc.w;
    if (lane == 0) { lm[wave] = m; ls[wave] = s; }
    __syncthreads();

    const float M = fmaxf(fmaxf(lm[0], lm[1]), fmaxf(lm[2], lm[3]));
    const float w0 = fexp(lm[0] - M), w1 = fexp(lm[1] - M),
                w2 = fexp(lm[2] - M), w3 = fexp(lm[3] - M);
    const int pidx = chunk * BB + b;
    ctxp[(size_t)pidx * HH + tid] =
        lctx[0][tid] * w0 + lctx[1][tid] * w1 + lctx[2][tid] * w2 + lctx[3][tid] * w3;
    if (tid == 0) {
        mp[pidx] = M;
        sp[pidx] = ls[0] * w0 + ls[1] * w1 + ls[2] * w2 + ls[3] * w3;
    }
}

// ---------------------------------------------------------------------------
// Per-step serial part. Grid: BB blocks (one per batch row), 256 threads.
// post_t >= 0: combine attention partials of step post_t -> ctx; write attns,
//              cov+=a, outs, pgens.
// post_t < 0:  init (load init_c/init_h, ctx=0, zero coverage).
// pre_t in [0,T): compute x, LSTM update (c,h), dec_feat for step pre_t.
// ---------------------------------------------------------------------------
__global__ __launch_bounds__(256) void step_kernel(
    const float* __restrict__ dec_in,  // (T,B,E)
    const float* __restrict__ init_c,  // (B,H)
    const float* __restrict__ init_h,  // (B,H)
    const float* __restrict__ mask,    // (B,L)
    const float* __restrict__ Wx, const float* __restrict__ bx,
    const float* __restrict__ Wl, const float* __restrict__ bl,
    const float* __restrict__ Ws, const float* __restrict__ bs,
    const float* __restrict__ Wp, const float* __restrict__ bp,
    const float* __restrict__ Wo, const float* __restrict__ bo,
    float* __restrict__ outs, float* __restrict__ c_out, float* __restrict__ h_out,
    float* __restrict__ attns, float* __restrict__ pgens, float* __restrict__ cov,
    const float* __restrict__ mp, const float* __restrict__ sp,
    const float* __restrict__ ctxp, const float* __restrict__ e_ws,
    float* __restrict__ x_ws, float* __restrict__ df_ws,
    int post_t, int pre_t)
{
    const int b = blockIdx.x;
    const int j = threadIdx.x;
    __shared__ float sctx[HH], scv[HH], shv[HH], sxv[EE], siv[EE];
    __shared__ float red[4];

    if (post_t >= 0) {
        scv[j] = c_out[b * HH + j];   // c_t
        shv[j] = h_out[b * HH + j];   // h_t
        // combine NCHUNK partials
        float M = -INFINITY;
        #pragma unroll
        for (int k = 0; k < NCHUNK; ++k) M = fmaxf(M, mp[k * BB + b]);
        float S = 0.f, cs = 0.f;
        #pragma unroll
        for (int k = 0; k < NCHUNK; ++k) {
            const float w = fexp(mp[k * BB + b] - M);
            S += sp[k * BB + b] * w;
            cs += ctxp[(size_t)(k * BB + b) * HH + j] * w;
        }
        const float invS = 1.f / S;
        sctx[j] = cs * invS;
        __syncthreads();

        // attention weights + coverage update
        for (int i = 0; i < LL / 256; ++i) {
            const int l = i * 256 + j;
            const float a = fexp(e_ws[b * LL + l] - M) * mask[b * LL + l] * invS;
            attns[((size_t)post_t * BB + b) * LL + l] = a;
            cov[b * LL + l] += a;
        }

        // out = [h, ctx] @ W_o + b_o
        float o = bo[j];
        for (int r = 0; r < HH; ++r) o += shv[r] * Wo[r * HH + j];
        for (int r = 0; r < HH; ++r) o += sctx[r] * Wo[(HH + r) * HH + j];
        outs[((size_t)post_t * BB + b) * HH + j] = o;

        // p_gen = sigmoid([ctx, c, h, x] @ W_p + b_p)
        float pp = sctx[j] * Wp[j] + scv[j] * Wp[HH + j] + shv[j] * Wp[2 * HH + j];
        if (j < EE) pp += x_ws[b * EE + j] * Wp[3 * HH + j];
        #pragma unroll
        for (int off = 32; off; off >>= 1) pp += __shfl_xor(pp, off);
        if ((j & 63) == 0) red[j >> 6] = pp;
        __syncthreads();
        if (j == 0)
            pgens[(size_t)post_t * BB + b] = fsig(red[0] + red[1] + red[2] + red[3] + bp[0]);
        __syncthreads();
    } else {
        // init: carry = (init_c, init_h, cov=0, ctx=0)
        scv[j] = init_c[b * HH + j];
        shv[j] = init_h[b * HH + j];
        sctx[j] = 0.f;
        for (int i = 0; i < LL / 256; ++i) cov[b * LL + i * 256 + j] = 0.f;
        __syncthreads();
    }

    if (pre_t >= 0 && pre_t < T_STEPS) {
        if (j < EE) siv[j] = dec_in[((size_t)pre_t * BB + b) * EE + j];
        __syncthreads();
        // x = relu([inp, ctx] @ W_x + b_x)
        if (j < EE) {
            float xv = bx[j];
            for (int r = 0; r < EE; ++r) xv += siv[r] * Wx[r * EE + j];
            for (int r = 0; r < HH; ++r) xv += sctx[r] * Wx[(EE + r) * EE + j];
            xv = fmaxf(xv, 0.f);
            sxv[j] = xv;
            x_ws[b * EE + j] = xv;
        }
        __syncthreads();
        // z = [x, h] @ W_lstm + b_lstm; gate order i,f,g,o
        float zi = bl[j], zf = bl[HH + j], zg = bl[2 * HH + j], zo = bl[3 * HH + j];
        for (int r = 0; r < EE; ++r) {
            const float xr = sxv[r];
            const float* wrow = Wl + (size_t)r * 4 * HH;
            zi += xr * wrow[j];
            zf += xr * wrow[HH + j];
            zg += xr * wrow[2 * HH + j];
            zo += xr * wrow[3 * HH + j];
        }
        for (int r = 0; r < HH; ++r) {
            const float hr = shv[r];
            const float* wrow = Wl + (size_t)(EE + r) * 4 * HH;
            zi += hr * wrow[j];
            zf += hr * wrow[HH + j];
            zg += hr * wrow[2 * HH + j];
            zo += hr * wrow[3 * HH + j];
        }
        const float cn = fsig(zf) * scv[j] + fsig(zi) * ftanh(zg);
        const float hn = fsig(zo) * ftanh(cn);
        c_out[b * HH + j] = cn;
        h_out[b * HH + j] = hn;
        __syncthreads();
        scv[j] = cn;
        shv[j] = hn;
        __syncthreads();
        // dec_feat = tanh([c, h] @ W_s + b_s)
        float d = bs[j];
        for (int r = 0; r < HH; ++r) d += scv[r] * Ws[r * HH + j];
        for (int r = 0; r < HH; ++r) d += shv[r] * Ws[(HH + r) * HH + j];
        df_ws[b * HH + j] = ftanh(d);
    }
}

extern "C" void kernel_launch(void* const* d_in, const int* in_sizes, int n_in,
                              void* d_out, int out_size, void* d_ws, size_t ws_size,
                              hipStream_t stream) {
    const float* dec_in = (const float*)d_in[0];
    const float* init_c = (const float*)d_in[1];
    const float* init_h = (const float*)d_in[2];
    const float* enc    = (const float*)d_in[3];
    const float* mask   = (const float*)d_in[4];
    const float* Wx = (const float*)d_in[5];
    const float* bx = (const float*)d_in[6];
    const float* Wl = (const float*)d_in[7];
    const float* bl = (const float*)d_in[8];
    const float* Ws = (const float*)d_in[9];
    const float* bs = (const float*)d_in[10];
    const float* v  = (const float*)d_in[11];
    const float* wc = (const float*)d_in[12];
    const float* Wp = (const float*)d_in[13];
    const float* bp = (const float*)d_in[14];
    const float* Wo = (const float*)d_in[15];
    const float* bo = (const float*)d_in[16];

    float* out   = (float*)d_out;
    float* outs  = out;                                   // T*B*H
    float* c_out = outs + (size_t)T_STEPS * BB * HH;      // B*H
    float* h_out = c_out + BB * HH;                       // B*H
    float* attns = h_out + BB * HH;                       // T*B*L
    float* pgens = attns + (size_t)T_STEPS * BB * LL;     // T*B
    float* cov   = pgens + T_STEPS * BB;                  // B*L

    float* ws    = (float*)d_ws;
    float* e_ws  = ws;                                    // B*L
    float* mp    = e_ws + BB * LL;                        // NCHUNK*B
    float* sp    = mp + NCHUNK * BB;                      // NCHUNK*B
    float* ctxp  = sp + NCHUNK * BB;                      // NCHUNK*B*H
    float* x_ws  = ctxp + (size_t)NCHUNK * BB * HH;       // B*E
    float* df_ws = x_ws + BB * EE;                        // B*H

    // init: carry_{-1}; computes x_0, (c_0,h_0), dec_feat_0
    step_kernel<<<BB, 256, 0, stream>>>(dec_in, init_c, init_h, mask,
        Wx, bx, Wl, bl, Ws, bs, Wp, bp, Wo, bo,
        outs, c_out, h_out, attns, pgens, cov,
        mp, sp, ctxp, e_ws, x_ws, df_ws, -1, 0);

    for (int t = 0; t < T_STEPS; ++t) {
        attn_kernel<<<NCHUNK * BB, 256, 0, stream>>>(
            enc, mask, cov, df_ws, v, wc, e_ws, mp, sp, ctxp);
        step_kernel<<<BB, 256, 0, stream>>>(dec_in, init_c, init_h, mask,
            Wx, bx, Wl, bl, Ws, bs, Wp, bp, Wo, bo,
            outs, c_out, h_out, attns, pgens, cov,
            mp, sp, ctxp, e_ws, x_ws, df_ws, t, t + 1);
    }
}

// Round 2
// 5873.904 us; speedup vs baseline: 1.0310x; 1.0310x over previous
//
#include <hip/hip_runtime.h>
#include <math.h>

#define T_STEPS 64
#define BB 64
#define LL 2048
#define EE 128
#define HH 256
#define NCHUNK 16
#define LCHUNK (LL / NCHUNK) /* 128 */

__device__ __forceinline__ float fexp(float x) {
    // e^x = 2^(x*log2e); exp2(-inf)=0 as needed for online-softmax init
    return __builtin_amdgcn_exp2f(x * 1.44269504088896340736f);
}
__device__ __forceinline__ float fsig(float x) {
    return __builtin_amdgcn_rcpf(1.f + __builtin_amdgcn_exp2f(-1.44269504088896340736f * x));
}
__device__ __forceinline__ float ftanh(float x) {
    float xc = fminf(fmaxf(x, -20.f), 20.f);
    float p = __builtin_amdgcn_exp2f(2.885390081777926814f * xc); // e^{2x}
    return (p - 1.f) * __builtin_amdgcn_rcpf(p + 1.f);
}

// ---------------------------------------------------------------------------
// Attention main pass, retiled for short reduction chains.
// Wave = 4 row-subgroups (lsub = lane>>4) x 16 h-chunks (hc = lane&15).
// Per macro-iteration a wave completes 4 full l-rows (each lane: 16 h-elems
// of ONE row). e-reduction: 4 shuffles (xor 1,2,4,8) within the 16-lane
// group. Each lane keeps private online-softmax state (m, s, cacc[16]);
// cross-subgroup combine (xor 16,32) once at loop end.
// Grid: NCHUNK*BB blocks (chunk = bid>>6, b = bid&63), 256 threads (4 waves).
// ---------------------------------------------------------------------------
__global__ __launch_bounds__(256) void attn_kernel(
    const float* __restrict__ enc,   // (B,L,H)
    const float* __restrict__ mask,  // (B,L)
    const float* __restrict__ covp,  // (B,L) current coverage
    const float* __restrict__ df,    // (B,H) dec_feat
    const float* __restrict__ v,     // (H)
    const float* __restrict__ wc,    // (H)
    float* __restrict__ e_ws,        // (B,L)
    float* __restrict__ mp,          // (NCHUNK*B)
    float* __restrict__ sp,          // (NCHUNK*B)
    float* __restrict__ ctxp)        // (NCHUNK*B*H)
{
    const int g = blockIdx.x;
    const int b = g & (BB - 1);
    const int chunk = g >> 6;
    const int tid = threadIdx.x;
    const int wave = tid >> 6;
    const int lane = tid & 63;
    const int hc = lane & 15;      // h-chunk: h = hc*4 + 64*k, k=0..3
    const int lsub = lane >> 4;    // row subgroup within wave
    const int l0 = chunk * LCHUNK + wave * (LCHUNK / 4);

    float4 df4[4], v4[4], wc4[4];
    #pragma unroll
    for (int k = 0; k < 4; ++k) {
        const int h = hc * 4 + 64 * k;
        df4[k] = *(const float4*)(df + b * HH + h);
        v4[k]  = *(const float4*)(v + h);
        wc4[k] = *(const float4*)(wc + h);
    }

    float m = -INFINITY, s = 0.f;
    float4 cacc[4];
    #pragma unroll
    for (int k = 0; k < 4; ++k) cacc[k] = make_float4(0.f, 0.f, 0.f, 0.f);

    for (int mi = 0; mi < LCHUNK / 16; ++mi) {   // 8 macro-iterations
        const int l = l0 + mi * 4 + lsub;
        const float cv  = covp[b * LL + l];
        const float msk = mask[b * LL + l];
        const float4* ep = (const float4*)(enc + (size_t)(b * LL + l) * HH) + hc;

        float4 ev[4];
        float p = 0.f;
        #pragma unroll
        for (int k = 0; k < 4; ++k) {
            ev[k] = ep[16 * k];
            const float t0 = ftanh(ev[k].x + df4[k].x + cv * wc4[k].x);
            const float t1 = ftanh(ev[k].y + df4[k].y + cv * wc4[k].y);
            const float t2 = ftanh(ev[k].z + df4[k].z + cv * wc4[k].z);
            const float t3 = ftanh(ev[k].w + df4[k].w + cv * wc4[k].w);
            p += v4[k].x * t0 + v4[k].y * t1 + v4[k].z * t2 + v4[k].w * t3;
        }
        // reduce over the 16-lane h-group (xor<16 stays within group)
        p += __shfl_xor(p, 1);
        p += __shfl_xor(p, 2);
        p += __shfl_xor(p, 4);
        p += __shfl_xor(p, 8);
        if (hc == 0) e_ws[b * LL + l] = p;

        // per-lane online-softmax update (p uniform within the 16-lane group)
        const float mn = fmaxf(m, p);
        const float sc = fexp(m - mn);       // 0 on first iter (m=-inf)
        const float w  = fexp(p - mn) * msk;
        s = s * sc + w;
        #pragma unroll
        for (int k = 0; k < 4; ++k) {
            cacc[k].x = cacc[k].x * sc + w * ev[k].x;
            cacc[k].y = cacc[k].y * sc + w * ev[k].y;
            cacc[k].z = cacc[k].z * sc + w * ev[k].z;
            cacc[k].w = cacc[k].w * sc + w * ev[k].w;
        }
        m = mn;
    }

    // combine the 4 row-subgroups: butterfly xor 16, 32 with max-rescale.
    // Lanes with equal hc hold identical h positions.
    #pragma unroll
    for (int off = 16; off <= 32; off <<= 1) {
        const float m2 = __shfl_xor(m, off);
        const float s2 = __shfl_xor(s, off);
        const float mn = fmaxf(m, m2);
        const float wa = fexp(m - mn), wb = fexp(m2 - mn);
        s = s * wa + s2 * wb;
        #pragma unroll
        for (int k = 0; k < 4; ++k) {
            float4 c2;
            c2.x = __shfl_xor(cacc[k].x, off);
            c2.y = __shfl_xor(cacc[k].y, off);
            c2.z = __shfl_xor(cacc[k].z, off);
            c2.w = __shfl_xor(cacc[k].w, off);
            cacc[k].x = cacc[k].x * wa + c2.x * wb;
            cacc[k].y = cacc[k].y * wa + c2.y * wb;
            cacc[k].z = cacc[k].z * wa + c2.z * wb;
            cacc[k].w = cacc[k].w * wa + c2.w * wb;
        }
        m = mn;
    }

    // block-level combine of the 4 wave partials via LDS
    __shared__ float lm[4], lsum[4];
    __shared__ float lctx[4][HH];
    if (lsub == 0) {
        #pragma unroll
        for (int k = 0; k < 4; ++k)
            *(float4*)&lctx[wave][hc * 4 + 64 * k] = cacc[k];
    }
    if (lane == 0) { lm[wave] = m; lsum[wave] = s; }
    __syncthreads();

    const float M = fmaxf(fmaxf(lm[0], lm[1]), fmaxf(lm[2], lm[3]));
    const float w0 = fexp(lm[0] - M), w1 = fexp(lm[1] - M),
                w2 = fexp(lm[2] - M), w3 = fexp(lm[3] - M);
    const int pidx = chunk * BB + b;
    ctxp[(size_t)pidx * HH + tid] =
        lctx[0][tid] * w0 + lctx[1][tid] * w1 + lctx[2][tid] * w2 + lctx[3][tid] * w3;
    if (tid == 0) {
        mp[pidx] = M;
        sp[pidx] = lsum[0] * w0 + lsum[1] * w1 + lsum[2] * w2 + lsum[3] * w3;
    }
}

// ---------------------------------------------------------------------------
// Per-step serial part. Grid: BB blocks (one per batch row), 256 threads.
// post_t >= 0: combine attention partials of step post_t -> ctx; write attns,
//              cov+=a, outs, pgens.
// post_t < 0:  init (load init_c/init_h, ctx=0, zero coverage).
// pre_t in [0,T): compute x, LSTM update (c,h), dec_feat for step pre_t.
// ---------------------------------------------------------------------------
__global__ __launch_bounds__(256) void step_kernel(
    const float* __restrict__ dec_in,  // (T,B,E)
    const float* __restrict__ init_c,  // (B,H)
    const float* __restrict__ init_h,  // (B,H)
    const float* __restrict__ mask,    // (B,L)
    const float* __restrict__ Wx, const float* __restrict__ bx,
    const float* __restrict__ Wl, const float* __restrict__ bl,
    const float* __restrict__ Ws, const float* __restrict__ bs,
    const float* __restrict__ Wp, const float* __restrict__ bp,
    const float* __restrict__ Wo, const float* __restrict__ bo,
    float* __restrict__ outs, float* __restrict__ c_out, float* __restrict__ h_out,
    float* __restrict__ attns, float* __restrict__ pgens, float* __restrict__ cov,
    const float* __restrict__ mp, const float* __restrict__ sp,
    const float* __restrict__ ctxp, const float* __restrict__ e_ws,
    float* __restrict__ x_ws, float* __restrict__ df_ws,
    int post_t, int pre_t)
{
    const int b = blockIdx.x;
    const int j = threadIdx.x;
    __shared__ float sctx[HH], scv[HH], shv[HH], sxv[EE], siv[EE];
    __shared__ float red[4];

    if (post_t >= 0) {
        scv[j] = c_out[b * HH + j];   // c_t
        shv[j] = h_out[b * HH + j];   // h_t
        // combine NCHUNK partials
        float M = -INFINITY;
        #pragma unroll
        for (int k = 0; k < NCHUNK; ++k) M = fmaxf(M, mp[k * BB + b]);
        float S = 0.f, cs = 0.f;
        #pragma unroll
        for (int k = 0; k < NCHUNK; ++k) {
            const float w = fexp(mp[k * BB + b] - M);
            S += sp[k * BB + b] * w;
            cs += ctxp[(size_t)(k * BB + b) * HH + j] * w;
        }
        const float invS = 1.f / S;
        sctx[j] = cs * invS;
        __syncthreads();

        // attention weights + coverage update
        for (int i = 0; i < LL / 256; ++i) {
            const int l = i * 256 + j;
            const float a = fexp(e_ws[b * LL + l] - M) * mask[b * LL + l] * invS;
            attns[((size_t)post_t * BB + b) * LL + l] = a;
            cov[b * LL + l] += a;
        }

        // out = [h, ctx] @ W_o + b_o
        float o = bo[j];
        for (int r = 0; r < HH; ++r) o += shv[r] * Wo[r * HH + j];
        for (int r = 0; r < HH; ++r) o += sctx[r] * Wo[(HH + r) * HH + j];
        outs[((size_t)post_t * BB + b) * HH + j] = o;

        // p_gen = sigmoid([ctx, c, h, x] @ W_p + b_p)
        float pp = sctx[j] * Wp[j] + scv[j] * Wp[HH + j] + shv[j] * Wp[2 * HH + j];
        if (j < EE) pp += x_ws[b * EE + j] * Wp[3 * HH + j];
        #pragma unroll
        for (int off = 32; off; off >>= 1) pp += __shfl_xor(pp, off);
        if ((j & 63) == 0) red[j >> 6] = pp;
        __syncthreads();
        if (j == 0)
            pgens[(size_t)post_t * BB + b] = fsig(red[0] + red[1] + red[2] + red[3] + bp[0]);
        __syncthreads();
    } else {
        // init: carry = (init_c, init_h, cov=0, ctx=0)
        scv[j] = init_c[b * HH + j];
        shv[j] = init_h[b * HH + j];
        sctx[j] = 0.f;
        for (int i = 0; i < LL / 256; ++i) cov[b * LL + i * 256 + j] = 0.f;
        __syncthreads();
    }

    if (pre_t >= 0 && pre_t < T_STEPS) {
        if (j < EE) siv[j] = dec_in[((size_t)pre_t * BB + b) * EE + j];
        __syncthreads();
        // x = relu([inp, ctx] @ W_x + b_x)
        if (j < EE) {
            float xv = bx[j];
            for (int r = 0; r < EE; ++r) xv += siv[r] * Wx[r * EE + j];
            for (int r = 0; r < HH; ++r) xv += sctx[r] * Wx[(EE + r) * EE + j];
            xv = fmaxf(xv, 0.f);
            sxv[j] = xv;
            x_ws[b * EE + j] = xv;
        }
        __syncthreads();
        // z = [x, h] @ W_lstm + b_lstm; gate order i,f,g,o
        float zi = bl[j], zf = bl[HH + j], zg = bl[2 * HH + j], zo = bl[3 * HH + j];
        for (int r = 0; r < EE; ++r) {
            const float xr = sxv[r];
            const float* wrow = Wl + (size_t)r * 4 * HH;
            zi += xr * wrow[j];
            zf += xr * wrow[HH + j];
            zg += xr * wrow[2 * HH + j];
            zo += xr * wrow[3 * HH + j];
        }
        for (int r = 0; r < HH; ++r) {
            const float hr = shv[r];
            const float* wrow = Wl + (size_t)(EE + r) * 4 * HH;
            zi += hr * wrow[j];
            zf += hr * wrow[HH + j];
            zg += hr * wrow[2 * HH + j];
            zo += hr * wrow[3 * HH + j];
        }
        const float cn = fsig(zf) * scv[j] + fsig(zi) * ftanh(zg);
        const float hn = fsig(zo) * ftanh(cn);
        c_out[b * HH + j] = cn;
        h_out[b * HH + j] = hn;
        __syncthreads();
        scv[j] = cn;
        shv[j] = hn;
        __syncthreads();
        // dec_feat = tanh([c, h] @ W_s + b_s)
        float d = bs[j];
        for (int r = 0; r < HH; ++r) d += scv[r] * Ws[r * HH + j];
        for (int r = 0; r < HH; ++r) d += shv[r] * Ws[(HH + r) * HH + j];
        df_ws[b * HH + j] = ftanh(d);
    }
}

extern "C" void kernel_launch(void* const* d_in, const int* in_sizes, int n_in,
                              void* d_out, int out_size, void* d_ws, size_t ws_size,
                              hipStream_t stream) {
    const float* dec_in = (const float*)d_in[0];
    const float* init_c = (const float*)d_in[1];
    const float* init_h = (const float*)d_in[2];
    const float* enc    = (const float*)d_in[3];
    const float* mask   = (const float*)d_in[4];
    const float* Wx = (const float*)d_in[5];
    const float* bx = (const float*)d_in[6];
    const float* Wl = (const float*)d_in[7];
    const float* bl = (const float*)d_in[8];
    const float* Ws = (const float*)d_in[9];
    const float* bs = (const float*)d_in[10];
    const float* v  = (const float*)d_in[11];
    const float* wc = (const float*)d_in[12];
    const float* Wp = (const float*)d_in[13];
    const float* bp = (const float*)d_in[14];
    const float* Wo = (const float*)d_in[15];
    const float* bo = (const float*)d_in[16];

    float* out   = (float*)d_out;
    float* outs  = out;                                   // T*B*H
    float* c_out = outs + (size_t)T_STEPS * BB * HH;      // B*H
    float* h_out = c_out + BB * HH;                       // B*H
    float* attns = h_out + BB * HH;                       // T*B*L
    float* pgens = attns + (size_t)T_STEPS * BB * LL;     // T*B
    float* cov   = pgens + T_STEPS * BB;                  // B*L

    float* ws    = (float*)d_ws;
    float* e_ws  = ws;                                    // B*L
    float* mp    = e_ws + BB * LL;                        // NCHUNK*B
    float* sp    = mp + NCHUNK * BB;                      // NCHUNK*B
    float* ctxp  = sp + NCHUNK * BB;                      // NCHUNK*B*H
    float* x_ws  = ctxp + (size_t)NCHUNK * BB * HH;       // B*E
    float* df_ws = x_ws + BB * EE;                        // B*H

    // init: carry_{-1}; computes x_0, (c_0,h_0), dec_feat_0
    step_kernel<<<BB, 256, 0, stream>>>(dec_in, init_c, init_h, mask,
        Wx, bx, Wl, bl, Ws, bs, Wp, bp, Wo, bo,
        outs, c_out, h_out, attns, pgens, cov,
        mp, sp, ctxp, e_ws, x_ws, df_ws, -1, 0);

    for (int t = 0; t < T_STEPS; ++t) {
        attn_kernel<<<NCHUNK * BB, 256, 0, stream>>>(
            enc, mask, cov, df_ws, v, wc, e_ws, mp, sp, ctxp);
        step_kernel<<<BB, 256, 0, stream>>>(dec_in, init_c, init_h, mask,
            Wx, bx, Wl, bl, Ws, bs, Wp, bp, Wo, bo,
            outs, c_out, h_out, attns, pgens, cov,
            mp, sp, ctxp, e_ws, x_ws, df_ws, t, t + 1);
    }
}